// Round 3
// baseline (45020.572 us; speedup 1.0000x reference)
//
#include <hip/hip_runtime.h>
#include <math.h>

// MPNN: B=32, N=1000, W=4, D=128 -> N_TOTAL=128000 node states of 128 fp32.
// R3: fp32 atomics proved to be per-lane line-granularity memory-side ops
// (~380B traffic per lane-atomic, 39GB per edge dispatch). Replaced with:
//   edge MLP -> materialized msg[2E][128] (streaming writes)
//   CSR (hist + 2-level scan + fill, rebuilt each launch; int atomics only)
//   aggregate: wave-per-node coalesced gather-sum of msg rows
// Fallback to atomic path if ws_size too small.

#define DDIM 128
#define NTOT 128000
#define HBYTES 65536000ULL            // 128000*128*4
#define MSGROWS 400128                // 2*E_INT padded to grid
#define MSGBYTES ((size_t)MSGROWS * 512)

__device__ __forceinline__ float gelu_exact(float x) {
    return 0.5f * x * (1.0f + erff(x * 0.70710678118654752440f));
}

__global__ __launch_bounds__(256) void embed_kernel(
    const int* __restrict__ inp, const float* __restrict__ table,
    float* __restrict__ h)
{
    int gid = blockIdx.x * 256 + threadIdx.x;     // over 128000*32 float4s
    if (gid >= NTOT * 32) return;
    int row = gid >> 5;
    int q   = gid & 31;
    int b   = row / 4000;
    int n   = (row % 4000) % 1000;
    int e   = inp[b * 1000 + n];
    ((float4*)h)[gid] = ((const float4*)table)[e * 32 + q];
}

// deg[seg]++ over seg = concat(bi, ni)
__global__ __launch_bounds__(256) void hist_kernel(
    const int* __restrict__ ni, const int* __restrict__ bi, int E,
    int* __restrict__ deg)
{
    int g = blockIdx.x * 256 + threadIdx.x;
    if (g < E)          atomicAdd(&deg[bi[g]], 1);
    else if (g < 2 * E) atomicAdd(&deg[ni[g - E]], 1);
}

// per-256-block exclusive scan of deg; block sums out
__global__ __launch_bounds__(256) void blockscan_kernel(
    const int* __restrict__ deg, int* __restrict__ offp, int* __restrict__ bsum)
{
    __shared__ int s[256];
    int tid = threadIdx.x;
    int i = blockIdx.x * 256 + tid;
    int v = deg[i];
    s[tid] = v;
    __syncthreads();
    for (int off = 1; off < 256; off <<= 1) {
        int t = (tid >= off) ? s[tid - off] : 0;
        __syncthreads();
        s[tid] += t;
        __syncthreads();
    }
    offp[i] = s[tid] - v;               // exclusive within block
    if (tid == 255) bsum[blockIdx.x] = s[255];
}

// single-block exclusive scan of 500 block sums
__global__ __launch_bounds__(512) void bscan_kernel(
    const int* __restrict__ bsum, int* __restrict__ bexc, int nb)
{
    __shared__ int s[512];
    int t = threadIdx.x;
    int v = (t < nb) ? bsum[t] : 0;
    s[t] = v;
    __syncthreads();
    for (int off = 1; off < 512; off <<= 1) {
        int u = (t >= off) ? s[t - off] : 0;
        __syncthreads();
        s[t] += u;
        __syncthreads();
    }
    if (t < nb) bexc[t] = s[t] - v;
}

__global__ __launch_bounds__(256) void fill_kernel(
    const int* __restrict__ ni, const int* __restrict__ bi, int E,
    const int* __restrict__ offp, const int* __restrict__ bexc,
    int* __restrict__ cursor, int* __restrict__ elist)
{
    int g = blockIdx.x * 256 + threadIdx.x;
    if (g >= 2 * E) return;
    int seg = (g < E) ? bi[g] : ni[g - E];
    int pos = atomicAdd(&cursor[seg], 1);
    elist[offp[seg] + bexc[seg >> 8] + pos] = g;
}

// Message MLP over 2E virtual rows -> msg[row][128] (streaming store).
// row<E: x=[h[ni]||h[bi]]; row>=E: x=[h[bi]||h[ni]]
__global__ __launch_bounds__(256, 3) void edge_mlp_kernel(
    const float* __restrict__ h,
    const int* __restrict__ ni, const int* __restrict__ bi, int E,
    const float* __restrict__ Win,  const float* __restrict__ bin,
    const float* __restrict__ Whid, const float* __restrict__ bhid,
    const float* __restrict__ Wout, const float* __restrict__ bout,
    float* __restrict__ msg)
{
    __shared__ float w[4096];         // 16KB weight chunk
    const int tid = threadIdx.x;
    const int row = blockIdx.x * 256 + tid;
    const bool valid = row < 2 * E;
    int first = 0, second = 0;
    if (valid) {
        if (row < E) { first = ni[row];     second = bi[row];     }
        else         { first = bi[row - E]; second = ni[row - E]; }
    }
    const float* rowp0 = h + (size_t)first  * DDIM;
    const float* rowp1 = h + (size_t)second * DDIM;

    // ---- stage 1: x[256] @ W_in[256x64] + b_in, gelu; 4 chunks ----
    float hcur[64];
    #pragma unroll
    for (int j = 0; j < 64; ++j) hcur[j] = bin[j];

    for (int c = 0; c < 4; ++c) {
        const float4* xb = (const float4*)((c < 2) ? rowp0 : rowp1) + (c & 1) * 16;
        float4 xv[8];
        #pragma unroll
        for (int q = 0; q < 8; ++q) xv[q] = xb[q];
        __syncthreads();
        for (int i4 = tid; i4 < 1024; i4 += 256)
            ((float4*)w)[i4] = ((const float4*)(Win + c * 4096))[i4];
        __syncthreads();
        #pragma unroll
        for (int q = 0; q < 8; ++q) {
            #pragma unroll
            for (int kk = 0; kk < 4; ++kk) {
                const float xk = (&xv[q].x)[kk];
                const float* wr = &w[(q * 4 + kk) * 64];
                #pragma unroll
                for (int j = 0; j < 64; ++j) hcur[j] = fmaf(xk, wr[j], hcur[j]);
            }
        }
        #pragma unroll
        for (int q = 0; q < 8; ++q) xv[q] = xb[8 + q];
        #pragma unroll
        for (int q = 0; q < 8; ++q) {
            #pragma unroll
            for (int kk = 0; kk < 4; ++kk) {
                const float xk = (&xv[q].x)[kk];
                const float* wr = &w[(32 + q * 4 + kk) * 64];
                #pragma unroll
                for (int j = 0; j < 64; ++j) hcur[j] = fmaf(xk, wr[j], hcur[j]);
            }
        }
    }
    #pragma unroll
    for (int j = 0; j < 64; ++j) hcur[j] = gelu_exact(hcur[j]);

    // ---- 3 hidden layers 64x64 ----
    for (int L = 0; L < 3; ++L) {
        __syncthreads();
        for (int i4 = tid; i4 < 1024; i4 += 256)
            ((float4*)w)[i4] = ((const float4*)(Whid + L * 4096))[i4];
        __syncthreads();
        float acc[64];
        #pragma unroll
        for (int j = 0; j < 64; ++j) acc[j] = bhid[L * 64 + j];
        #pragma unroll
        for (int k = 0; k < 64; ++k) {
            const float xk = hcur[k];
            const float* wr = &w[k * 64];
            #pragma unroll
            for (int j = 0; j < 64; ++j) acc[j] = fmaf(xk, wr[j], acc[j]);
        }
        #pragma unroll
        for (int j = 0; j < 64; ++j) hcur[j] = gelu_exact(acc[j]);
    }

    // ---- output layer 64x128 in two halves, streaming store ----
    for (int half = 0; half < 2; ++half) {
        __syncthreads();
        for (int i4 = tid; i4 < 1024; i4 += 256) {
            int k = i4 >> 4, jq = i4 & 15;
            ((float4*)w)[i4] = *(const float4*)(Wout + k * 128 + half * 64 + jq * 4);
        }
        __syncthreads();
        float acc[64];
        #pragma unroll
        for (int j = 0; j < 64; ++j) acc[j] = bout[half * 64 + j];
        #pragma unroll
        for (int k = 0; k < 64; ++k) {
            const float xk = hcur[k];
            const float* wr = &w[k * 64];
            #pragma unroll
            for (int j = 0; j < 64; ++j) acc[j] = fmaf(xk, wr[j], acc[j]);
        }
        float4* mp = (float4*)(msg + (size_t)row * DDIM + half * 64);
        #pragma unroll
        for (int j4 = 0; j4 < 16; ++j4)
            mp[j4] = make_float4(acc[j4 * 4], acc[j4 * 4 + 1],
                                 acc[j4 * 4 + 2], acc[j4 * 4 + 3]);
    }
}

// R2 fallback path (only used if ws_size is too small for msg buffer)
__global__ __launch_bounds__(256, 3) void edge_mlp_atomic_kernel(
    const float* __restrict__ h,
    const int* __restrict__ ni, const int* __restrict__ bi, int E,
    const float* __restrict__ Win,  const float* __restrict__ bin,
    const float* __restrict__ Whid, const float* __restrict__ bhid,
    const float* __restrict__ Wout, const float* __restrict__ bout,
    float* __restrict__ sbuf)
{
    __shared__ float w[4096];
    __shared__ float scat[4][1040];
    const int tid  = threadIdx.x;
    const int lane = tid & 63;
    const int wv   = tid >> 6;
    const int row  = blockIdx.x * 256 + tid;
    const bool valid = row < 2 * E;
    int first = 0, second = 0;
    if (valid) {
        if (row < E) { first = ni[row];     second = bi[row];     }
        else         { first = bi[row - E]; second = ni[row - E]; }
    }
    const int segv = valid ? second : -1;
    const float* rowp0 = h + (size_t)first  * DDIM;
    const float* rowp1 = h + (size_t)second * DDIM;

    float hcur[64];
    #pragma unroll
    for (int j = 0; j < 64; ++j) hcur[j] = bin[j];
    for (int c = 0; c < 4; ++c) {
        const float4* xb = (const float4*)((c < 2) ? rowp0 : rowp1) + (c & 1) * 16;
        float4 xv[8];
        #pragma unroll
        for (int q = 0; q < 8; ++q) xv[q] = xb[q];
        __syncthreads();
        for (int i4 = tid; i4 < 1024; i4 += 256)
            ((float4*)w)[i4] = ((const float4*)(Win + c * 4096))[i4];
        __syncthreads();
        #pragma unroll
        for (int q = 0; q < 8; ++q)
            #pragma unroll
            for (int kk = 0; kk < 4; ++kk) {
                const float xk = (&xv[q].x)[kk];
                const float* wr = &w[(q * 4 + kk) * 64];
                #pragma unroll
                for (int j = 0; j < 64; ++j) hcur[j] = fmaf(xk, wr[j], hcur[j]);
            }
        #pragma unroll
        for (int q = 0; q < 8; ++q) xv[q] = xb[8 + q];
        #pragma unroll
        for (int q = 0; q < 8; ++q)
            #pragma unroll
            for (int kk = 0; kk < 4; ++kk) {
                const float xk = (&xv[q].x)[kk];
                const float* wr = &w[(32 + q * 4 + kk) * 64];
                #pragma unroll
                for (int j = 0; j < 64; ++j) hcur[j] = fmaf(xk, wr[j], hcur[j]);
            }
    }
    #pragma unroll
    for (int j = 0; j < 64; ++j) hcur[j] = gelu_exact(hcur[j]);

    for (int L = 0; L < 3; ++L) {
        __syncthreads();
        for (int i4 = tid; i4 < 1024; i4 += 256)
            ((float4*)w)[i4] = ((const float4*)(Whid + L * 4096))[i4];
        __syncthreads();
        float acc[64];
        #pragma unroll
        for (int j = 0; j < 64; ++j) acc[j] = bhid[L * 64 + j];
        #pragma unroll
        for (int k = 0; k < 64; ++k) {
            const float xk = hcur[k];
            const float* wr = &w[k * 64];
            #pragma unroll
            for (int j = 0; j < 64; ++j) acc[j] = fmaf(xk, wr[j], acc[j]);
        }
        #pragma unroll
        for (int j = 0; j < 64; ++j) hcur[j] = gelu_exact(acc[j]);
    }

    for (int half = 0; half < 2; ++half) {
        __syncthreads();
        for (int i4 = tid; i4 < 1024; i4 += 256) {
            int k = i4 >> 4, jq = i4 & 15;
            ((float4*)w)[i4] = *(const float4*)(Wout + k * 128 + half * 64 + jq * 4);
        }
        __syncthreads();
        float acc[64];
        #pragma unroll
        for (int j = 0; j < 64; ++j) acc[j] = bout[half * 64 + j];
        #pragma unroll
        for (int k = 0; k < 64; ++k) {
            const float xk = hcur[k];
            const float* wr = &w[k * 64];
            #pragma unroll
            for (int j = 0; j < 64; ++j) acc[j] = fmaf(xk, wr[j], acc[j]);
        }
        for (int sub = 0; sub < 4; ++sub) {
            __syncthreads();
            if ((lane >> 4) == sub) {
                float* dp = &scat[wv][(lane & 15) * 65];
                #pragma unroll
                for (int j = 0; j < 64; ++j) dp[j] = acc[j];
            }
            __syncthreads();
            for (int r = 0; r < 16; ++r) {
                const int seg = __shfl(segv, sub * 16 + r);
                if (seg >= 0)
                    atomicAdd(sbuf + (size_t)seg * DDIM + half * 64 + lane,
                              scat[wv][r * 65 + lane]);
            }
        }
    }
}

// wave-per-node coalesced gather-sum of msg rows -> sbuf (SUM, not mean)
__global__ __launch_bounds__(256) void aggregate_kernel(
    const float* __restrict__ msg, const int* __restrict__ elist,
    const int* __restrict__ offp, const int* __restrict__ bexc,
    const int* __restrict__ deg, float* __restrict__ sbuf)
{
    const int node = blockIdx.x * 4 + (threadIdx.x >> 6);
    const int lane = threadIdx.x & 63;
    const int start = offp[node] + bexc[node >> 8];
    const int d = deg[node];
    float2 acc = make_float2(0.0f, 0.0f);
    for (int e = 0; e < d; ++e) {
        int m = elist[start + e];
        float2 v = ((const float2*)(msg + (size_t)m * DDIM))[lane];
        acc.x += v.x; acc.y += v.y;
    }
    ((float2*)(sbuf + (size_t)node * DDIM))[lane] = acc;
}

// Fused GRU (keras reset_after): hout = z*h + (1-z)*tanh(xh + r*hh)
// sbuf holds segment SUM; divide by max(deg,1).
__global__ __launch_bounds__(256) void gru_kernel(
    const float* __restrict__ h, const float* __restrict__ sbuf,
    const int* __restrict__ deg,
    const float* __restrict__ Wx, const float* __restrict__ Wh,
    const float* __restrict__ bi, const float* __restrict__ br,
    float* __restrict__ hout)
{
    __shared__ float w[12288];
    const int tid  = threadIdx.x;
    const int node = blockIdx.x * 256 + tid;
    const float cinv = 1.0f / fmaxf((float)deg[node], 1.0f);
    const float4* mrow = (const float4*)(sbuf + (size_t)node * DDIM);
    const float4* hrow = (const float4*)(h    + (size_t)node * DDIM);

    for (int c = 0; c < 8; ++c) {
        const int d0 = c * 16;
        for (int i = tid; i < 2048; i += 256) {
            int k = i >> 4, dd = i & 15;
            w[i]         = Wx[k * 384 +       d0 + dd];
            w[2048 + i]  = Wx[k * 384 + 128 + d0 + dd];
            w[4096 + i]  = Wx[k * 384 + 256 + d0 + dd];
            w[6144 + i]  = Wh[k * 384 +       d0 + dd];
            w[8192 + i]  = Wh[k * 384 + 128 + d0 + dd];
            w[10240 + i] = Wh[k * 384 + 256 + d0 + dd];
        }
        __syncthreads();

        float az[16], ar[16], axh[16], ahh[16];
        #pragma unroll
        for (int dd = 0; dd < 16; ++dd) {
            az[dd]  = bi[d0 + dd]       + br[d0 + dd];
            ar[dd]  = bi[128 + d0 + dd] + br[128 + d0 + dd];
            axh[dd] = bi[256 + d0 + dd];
            ahh[dd] = br[256 + d0 + dd];
        }
        for (int k4 = 0; k4 < 32; ++k4) {
            float4 m4 = mrow[k4];
            float4 h4 = hrow[k4];
            #pragma unroll
            for (int kk = 0; kk < 4; ++kk) {
                float mv = (&m4.x)[kk] * cinv;
                float hv = (&h4.x)[kk];
                const int kb = (k4 * 4 + kk) * 16;
                #pragma unroll
                for (int dd = 0; dd < 16; ++dd) {
                    az[dd]  = fmaf(mv, w[kb + dd],          az[dd]);
                    az[dd]  = fmaf(hv, w[6144 + kb + dd],   az[dd]);
                    ar[dd]  = fmaf(mv, w[2048 + kb + dd],   ar[dd]);
                    ar[dd]  = fmaf(hv, w[8192 + kb + dd],   ar[dd]);
                    axh[dd] = fmaf(mv, w[4096 + kb + dd],  axh[dd]);
                    ahh[dd] = fmaf(hv, w[10240 + kb + dd], ahh[dd]);
                }
            }
        }
        float4 hv4[4];
        #pragma unroll
        for (int q = 0; q < 4; ++q) hv4[q] = hrow[c * 4 + q];
        float4 o[4];
        #pragma unroll
        for (int dd = 0; dd < 16; ++dd) {
            float z    = 1.0f / (1.0f + expf(-az[dd]));
            float r    = 1.0f / (1.0f + expf(-ar[dd]));
            float cand = tanhf(axh[dd] + r * ahh[dd]);
            float hval = (&hv4[dd >> 2].x)[dd & 3];
            (&o[dd >> 2].x)[dd & 3] = z * hval + (1.0f - z) * cand;
        }
        float4* orow = (float4*)(hout + (size_t)node * DDIM + d0);
        #pragma unroll
        for (int q = 0; q < 4; ++q) orow[q] = o[q];
        __syncthreads();
    }
}

// block=64 (1 wave), grid=500; 16KB chunked weights; VGPR-capped (no spill)
__global__ __launch_bounds__(64, 3) void readout_kernel(
    const float* __restrict__ h,
    const float* __restrict__ Win,  const float* __restrict__ bin,
    const float* __restrict__ Whid, const float* __restrict__ bhid,
    const float* __restrict__ Wout, const float* __restrict__ bout,
    float* __restrict__ out)
{
    __shared__ float w[4096];
    const int tid = threadIdx.x;
    const int row = blockIdx.x * 64 + tid;        // 0..31999 exactly
    const int b = row / 1000, n = row % 1000;
    const float4* xrow = (const float4*)(h + ((size_t)b * 4000 + n) * DDIM);

    float hcur[64];
    #pragma unroll
    for (int j = 0; j < 64; ++j) hcur[j] = bin[j];

    for (int c = 0; c < 2; ++c) {                 // Win in 2 chunks of 64 rows
        __syncthreads();
        for (int i4 = tid; i4 < 1024; i4 += 64)
            ((float4*)w)[i4] = ((const float4*)(Win + c * 4096))[i4];
        __syncthreads();
        #pragma unroll
        for (int k4 = 0; k4 < 16; ++k4) {
            float4 xv = xrow[c * 16 + k4];
            #pragma unroll
            for (int kk = 0; kk < 4; ++kk) {
                float xk = (&xv.x)[kk];
                const float* wr = &w[(k4 * 4 + kk) * 64];
                #pragma unroll
                for (int j = 0; j < 64; ++j) hcur[j] = fmaf(xk, wr[j], hcur[j]);
            }
        }
    }
    #pragma unroll
    for (int j = 0; j < 64; ++j) hcur[j] = gelu_exact(hcur[j]);

    for (int L = 0; L < 3; ++L) {
        __syncthreads();
        for (int i4 = tid; i4 < 1024; i4 += 64)
            ((float4*)w)[i4] = ((const float4*)(Whid + L * 4096))[i4];
        __syncthreads();
        float acc[64];
        #pragma unroll
        for (int j = 0; j < 64; ++j) acc[j] = bhid[L * 64 + j];
        #pragma unroll
        for (int k = 0; k < 64; ++k) {
            float xk = hcur[k];
            const float* wr = &w[k * 64];
            #pragma unroll
            for (int j = 0; j < 64; ++j) acc[j] = fmaf(xk, wr[j], acc[j]);
        }
        #pragma unroll
        for (int j = 0; j < 64; ++j) hcur[j] = gelu_exact(acc[j]);
    }

    __syncthreads();
    for (int i = tid; i < 640; i += 64) w[i] = Wout[i];
    __syncthreads();

    float acc[10];
    #pragma unroll
    for (int p = 0; p < 10; ++p) acc[p] = bout[p];
    #pragma unroll
    for (int k = 0; k < 64; ++k) {
        float xk = hcur[k];
        #pragma unroll
        for (int p = 0; p < 10; ++p) acc[p] = fmaf(xk, w[k * 10 + p], acc[p]);
    }
    #pragma unroll
    for (int p = 0; p < 10; ++p) out[(size_t)row * 10 + p] = acc[p];
}

extern "C" void kernel_launch(void* const* d_in, const int* in_sizes, int n_in,
                              void* d_out, int out_size, void* d_ws, size_t ws_size,
                              hipStream_t stream) {
    const int*   node_inputs = (const int*)d_in[0];
    const int*   ni_int = (const int*)d_in[1];
    const int*   bi_int = (const int*)d_in[2];
    const int*   ni_tmp = (const int*)d_in[3];
    const int*   bi_tmp = (const int*)d_in[4];
    const float* embed  = (const float*)d_in[5];
    const float* mWin   = (const float*)d_in[6];
    const float* mbin   = (const float*)d_in[7];
    const float* mWhid  = (const float*)d_in[8];
    const float* mbhid  = (const float*)d_in[9];
    const float* mWout  = (const float*)d_in[10];
    const float* mbout  = (const float*)d_in[11];
    const float* roWin  = (const float*)d_in[12];
    const float* robin  = (const float*)d_in[13];
    const float* roWhid = (const float*)d_in[14];
    const float* robhid = (const float*)d_in[15];
    const float* roWout = (const float*)d_in[16];
    const float* robout = (const float*)d_in[17];
    const float* giWx = (const float*)d_in[18];
    const float* giWh = (const float*)d_in[19];
    const float* gibi = (const float*)d_in[20];
    const float* gibr = (const float*)d_in[21];
    const float* gtWx = (const float*)d_in[22];
    const float* gtWh = (const float*)d_in[23];
    const float* gtbi = (const float*)d_in[24];
    const float* gtbr = (const float*)d_in[25];
    float* out = (float*)d_out;

    const int E_INT = 200000, E_TMP = 96000;

    char* ws = (char*)d_ws;
    float* hA   = (float*)(ws);
    float* hB   = (float*)(ws + HBYTES);
    float* sbuf = (float*)(ws + 2 * HBYTES);
    float* msg  = (float*)(ws + 3 * HBYTES);

    const size_t NEED = 3 * HBYTES + MSGBYTES + 8 * 1024 * 1024;
    const bool fast = (ws_size >= NEED);

    char* ib = ws + (fast ? (3 * HBYTES + MSGBYTES) : 3 * HBYTES);
    int* deg_i  = (int*)(ib);                       // 512000 B
    int* deg_t  = (int*)(ib + 512000);
    int* offp_i = (int*)(ib + 1024000);
    int* offp_t = (int*)(ib + 1536000);
    int* bexc_i = (int*)(ib + 2048000);             // 4096 B
    int* bexc_t = (int*)(ib + 2052096);
    int* bsum   = (int*)(ib + 2056192);             // 4096 B
    int* cursor = (int*)(ib + 2060288);             // 512000 B
    int* el_i   = (int*)(ib + 2572288);             // 1.6 MB
    int* el_t   = (int*)(ib + 4172288);             // 768 KB

    embed_kernel<<<16000, 256, 0, stream>>>(node_inputs, embed, hA);

    // degrees (needed by both paths)
    hipMemsetAsync(deg_i, 0, NTOT * sizeof(int), stream);
    hipMemsetAsync(deg_t, 0, NTOT * sizeof(int), stream);
    hist_kernel<<<(2 * E_INT + 255) / 256, 256, 0, stream>>>(ni_int, bi_int, E_INT, deg_i);
    hist_kernel<<<(2 * E_TMP + 255) / 256, 256, 0, stream>>>(ni_tmp, bi_tmp, E_TMP, deg_t);

    if (fast) {
        // CSR for both edge sets
        blockscan_kernel<<<500, 256, 0, stream>>>(deg_i, offp_i, bsum);
        bscan_kernel<<<1, 512, 0, stream>>>(bsum, bexc_i, 500);
        hipMemsetAsync(cursor, 0, NTOT * sizeof(int), stream);
        fill_kernel<<<(2 * E_INT + 255) / 256, 256, 0, stream>>>(
            ni_int, bi_int, E_INT, offp_i, bexc_i, cursor, el_i);

        blockscan_kernel<<<500, 256, 0, stream>>>(deg_t, offp_t, bsum);
        bscan_kernel<<<1, 512, 0, stream>>>(bsum, bexc_t, 500);
        hipMemsetAsync(cursor, 0, NTOT * sizeof(int), stream);
        fill_kernel<<<(2 * E_TMP + 255) / 256, 256, 0, stream>>>(
            ni_tmp, bi_tmp, E_TMP, offp_t, bexc_t, cursor, el_t);
    }

    float* hc = hA;
    float* hn = hB;
    for (int t = 0; t < 2; ++t) {
        // interaction phase
        if (fast) {
            edge_mlp_kernel<<<(2 * E_INT + 255) / 256, 256, 0, stream>>>(
                hc, ni_int, bi_int, E_INT,
                mWin, mbin, mWhid, mbhid, mWout, mbout, msg);
            aggregate_kernel<<<NTOT / 4, 256, 0, stream>>>(
                msg, el_i, offp_i, bexc_i, deg_i, sbuf);
        } else {
            hipMemsetAsync(sbuf, 0, HBYTES, stream);
            edge_mlp_atomic_kernel<<<(2 * E_INT + 255) / 256, 256, 0, stream>>>(
                hc, ni_int, bi_int, E_INT,
                mWin, mbin, mWhid, mbhid, mWout, mbout, sbuf);
        }
        gru_kernel<<<NTOT / 256, 256, 0, stream>>>(
            hc, sbuf, deg_i, giWx, giWh, gibi, gibr, hn);
        { float* tmp = hc; hc = hn; hn = tmp; }

        // temporal phase
        if (fast) {
            edge_mlp_kernel<<<(2 * E_TMP + 255) / 256, 256, 0, stream>>>(
                hc, ni_tmp, bi_tmp, E_TMP,
                mWin, mbin, mWhid, mbhid, mWout, mbout, msg);
            aggregate_kernel<<<NTOT / 4, 256, 0, stream>>>(
                msg, el_t, offp_t, bexc_t, deg_t, sbuf);
        } else {
            hipMemsetAsync(sbuf, 0, HBYTES, stream);
            edge_mlp_atomic_kernel<<<(2 * E_TMP + 255) / 256, 256, 0, stream>>>(
                hc, ni_tmp, bi_tmp, E_TMP,
                mWin, mbin, mWhid, mbhid, mWout, mbout, sbuf);
        }
        gru_kernel<<<NTOT / 256, 256, 0, stream>>>(
            hc, sbuf, deg_t, gtWx, gtWh, gtbi, gtbr, hn);
        { float* tmp = hc; hc = hn; hn = tmp; }
    }

    readout_kernel<<<500, 64, 0, stream>>>(
        hc, roWin, robin, roWhid, robhid, roWout, robout, out);
}